// Round 11
// baseline (582.005 us; speedup 1.0000x reference)
//
#include <hip/hip_runtime.h>

constexpr int N     = 3072;
constexpr int S     = 32;
constexpr int E     = 4;
constexpr int FIN   = 64;
constexpr int CAP   = 64;     // max sources per (e,n); Binomial(3072,0.005) mean 15.4, P(>=64)~1e-19
constexpr int NNi   = N * N;  // 9,437,184
constexpr int DUMMY = N;      // extra all-zero h row for gather padding
constexpr int BLK   = 256;    // 1 block/CU
constexpr int TPB   = 768;    // 12 waves = 12 nodes per block; 256*12 = 3072
constexpr int NPB   = 12;

typedef float vfloat2 __attribute__((ext_vector_type(2)));

__device__ __forceinline__ vfloat2 vfma2(vfloat2 a, vfloat2 b, vfloat2 c) {
#if __has_builtin(__builtin_elementwise_fma)
    return __builtin_elementwise_fma(a, b, c);   // lowers to v_pk_fma_f32
#else
    vfloat2 r; r.x = fmaf(a.x, b.x, c.x); r.y = fmaf(a.y, b.y, c.y); return r;
#endif
}

__device__ __forceinline__ float rl(float v, int lane) {   // wave-uniform broadcast via VALU
    return __int_as_float(__builtin_amdgcn_readlane(__float_as_int(v), lane));
}
__device__ __forceinline__ float fast_sigmoid(float x) {
    x = fminf(fmaxf(x, -30.f), 30.f);
    return 1.f / (1.f + __expf(-x));
}
__device__ __forceinline__ float fast_tanh(float x) {
    x = fminf(fmaxf(x, -15.f), 15.f);
    float e = __expf(2.f * x);
    return (e - 1.f) / (e + 1.f);
}

// Cache-bypassing accessors: relaxed AGENT-scope atomics are coherent at the
// memory-side Infinity Cache (above the non-coherent per-XCD L2s).
__device__ __forceinline__ float ld_dev(const float* p) {
    return __hip_atomic_load((float*)p, __ATOMIC_RELAXED, __HIP_MEMORY_SCOPE_AGENT);
}
__device__ __forceinline__ void st_dev(float* p, float v) {
    __hip_atomic_store(p, v, __ATOMIC_RELAXED, __HIP_MEMORY_SCOPE_AGENT);
}

// Two-level monotone tree barrier (reset-free), 16 groups x 16 blocks.
__device__ __forceinline__ void gbar(int* bar, int ph, int b) {
    __syncthreads();          // compiler drains vmcnt(0) before s_barrier
    if (threadIdx.x == 0) {
        int* grp  = bar + (b >> 4) * 16;
        int* root = bar + 256;
        int* go   = bar + 272;
        int old = __hip_atomic_fetch_add(grp, 1, __ATOMIC_RELAXED, __HIP_MEMORY_SCOPE_AGENT);
        if (old + 1 == ph * 16) {
            int old2 = __hip_atomic_fetch_add(root, 1, __ATOMIC_RELAXED, __HIP_MEMORY_SCOPE_AGENT);
            if (old2 + 1 == ph * 16)
                __hip_atomic_store(go, ph, __ATOMIC_RELAXED, __HIP_MEMORY_SCOPE_AGENT);
        }
        int spins = 0;
        while (__hip_atomic_load(go, __ATOMIC_RELAXED, __HIP_MEMORY_SCOPE_AGENT) < ph) {
            __builtin_amdgcn_s_sleep(2);
            if (++spins > 300000) break;           // wedge -> terminate, not hang
        }
    }
    __syncthreads();
}

// ---------------------------------------------------------------------------
// Pass 1: dense fp32 adjacency -> CSR. Grid-stride (256x256, 144 float4/thread)
// to avoid 36.6k tiny-block dispatch overhead.
// ---------------------------------------------------------------------------
__global__ __launch_bounds__(256) void build_csr(const float* __restrict__ edges,
                                                 int* __restrict__ deg,
                                                 int* __restrict__ csr) {
    const float4* e4 = (const float4*)edges;
    for (int i = blockIdx.x * 256 + threadIdx.x; i < NNi * E / 4; i += 256 * 256) {
        float4 v = e4[i];
        if (v.x == 0.f && v.y == 0.f && v.z == 0.f && v.w == 0.f) continue;
        int idx4 = i * 4;
        int e   = idx4 / NNi;
        int rem = idx4 - e * NNi;
        int m   = rem / N;
        int nb  = rem - m * N;
        float w[4] = {v.x, v.y, v.z, v.w};
        int base = e * N + nb;
        #pragma unroll
        for (int j = 0; j < 4; ++j) {
            if (w[j] != 0.f) {
                int slot = base + j;
                int pos = atomicAdd(&deg[slot], 1);
                if (pos < CAP) csr[slot * CAP + pos] = m;
            }
        }
    }
}

struct Params {
    const float *x, *fcw, *fcb;
    const float *wz, *wr, *wh, *uz, *ur, *uh, *bz, *br;
    const float *ow, *ob;
    const int   *deg, *csr;
    int   *bar;
    float *h0, *h1, *out;
};

// ---------------------------------------------------------------------------
// Fused cooperative kernel: round-8 structure + packed-pair weight layout.
// LDS W layout: [mat][e][k2][s][2] (k-pairs adjacent) -> ds_read_b64 +
// v_pk_fma_f32 per k-pair: halves LDS instructions and FMA issue count.
// One wave per node; lane = (g,s); half g handles edge types {g, g+2} in the
// gather and the z (g=0) / r (g=1) gate.
// ---------------------------------------------------------------------------
__global__ __launch_bounds__(TPB, 3) void fused_ggnn(Params p) {
    __shared__ __align__(16) float sW[3 * 4096];   // [z|r|h][e][k2][s][2]
    __shared__ __align__(16) float sU[3 * 1024];   // [z|r|h][k2][s][2]
    __shared__ float sB[64];                       // [bz|br][s]

    const int tid  = threadIdx.x;
    const int b    = blockIdx.x;
    const int wid  = tid >> 6;
    const int lane = tid & 63;
    const int s    = lane & 31;
    const int g    = lane >> 5;
    const int n    = b * NPB + wid;

    // ---- init: h0 = x @ fc_w + fc_b, redundantly in both halves so hval
    // lives in a register for the whole kernel; store once (g==0).
    float hval;
    {
        float acc = p.fcb[s];
        #pragma unroll 8
        for (int k = 0; k < FIN; ++k)
            acc = fmaf(p.x[n * FIN + k], p.fcw[k * S + s], acc);
        hval = acc;
        if (g == 0) st_dev(&p.h0[n * S + s], acc);
    }
    if (b == 0) {                                  // zero dummy rows, both buffers
        if (tid < 32)      st_dev(&p.h0[DUMMY * S + tid], 0.f);
        else if (tid < 64) st_dev(&p.h1[DUMMY * S + (tid - 32)], 0.f);
    }

    // ---- iteration-invariant CSR state (prev-dispatch data: cached reads OK)
    const int slot1 = g * N + n;
    const int slot2 = (g + 2) * N + n;
    const int d1 = min(p.deg[slot1], CAP);
    const int d2 = min(p.deg[slot2], CAP);
    const int* __restrict__ l1 = p.csr + slot1 * CAP;
    const int* __restrict__ l2 = p.csr + slot2 * CAP;
    const int dm = max(d1, d2);

    const float* hp = p.h0;
    float*       hn = p.h1;
    int phase = 1;
    gbar(p.bar, phase, b); phase++;                // h0 device-visible

    for (int l = 0; l < 3; ++l) {
        __syncthreads();                           // guard LDS reuse across layers
        {
            // W: 3 mats x 2048 float2; pair k/k+1 into adjacent floats.
            const float* gsrc[3] = { p.wz + l * 4096, p.wr + l * 4096, p.wh + l * 4096 };
            for (int j = tid; j < 6144; j += TPB) {
                int mat = j >> 11;                 // /2048
                int r   = j & 2047;
                int e   = r >> 9;                  // 512 float2 per e
                int rr  = r & 511;
                int k2  = rr >> 5;
                int ss  = rr & 31;
                const float* src = gsrc[mat] + e * 1024 + (2 * k2) * 32 + ss;
                float2 val = { src[0], src[32] };
                *(float2*)(sW + mat * 4096 + e * 1024 + k2 * 64 + ss * 2) = val;
            }
            // U: 3 mats x 512 float2
            const float* usrc[3] = { p.uz + l * 1024, p.ur + l * 1024, p.uh + l * 1024 };
            for (int j = tid; j < 1536; j += TPB) {
                int mat = j >> 9;
                int rr  = j & 511;
                int k2  = rr >> 5;
                int ss  = rr & 31;
                const float* src = usrc[mat] + (2 * k2) * 32 + ss;
                float2 val = { src[0], src[32] };
                *(float2*)(sU + mat * 1024 + k2 * 64 + ss * 2) = val;
            }
            if (tid < 64) sB[tid] = (tid < 32) ? p.bz[l * 32 + tid]
                                               : p.br[l * 32 + (tid - 32)];
        }
        __syncthreads();

        for (int it = 0; it < 5; ++it) {
            // ---- phase A: sparse gather (round-8 chunk-4, proven)
            float acc0 = 0.f, acc1 = 0.f;
            for (int c = 0; c < dm; c += 4) {
                int4 ia = *reinterpret_cast<const int4*>(l1 + c);
                int4 ib = *reinterpret_cast<const int4*>(l2 + c);
                int r0 = (c + 0 < d1) ? ia.x : DUMMY;
                int r1 = (c + 1 < d1) ? ia.y : DUMMY;
                int r2 = (c + 2 < d1) ? ia.z : DUMMY;
                int r3 = (c + 3 < d1) ? ia.w : DUMMY;
                int q0 = (c + 0 < d2) ? ib.x : DUMMY;
                int q1 = (c + 1 < d2) ? ib.y : DUMMY;
                int q2 = (c + 2 < d2) ? ib.z : DUMMY;
                int q3 = (c + 3 < d2) ? ib.w : DUMMY;
                float v0 = ld_dev(hp + r0 * S + s), v1 = ld_dev(hp + r1 * S + s);
                float v2 = ld_dev(hp + r2 * S + s), v3 = ld_dev(hp + r3 * S + s);
                float u0 = ld_dev(hp + q0 * S + s), u1 = ld_dev(hp + q1 * S + s);
                float u2 = ld_dev(hp + q2 * S + s), u3 = ld_dev(hp + q3 * S + s);
                acc0 += (v0 + v1) + (v2 + v3);
                acc1 += (u0 + u1) + (u2 + u3);
            }

            // ---- phases B+C: z|r gate (split halves) + hh, packed-pair math
            const float* __restrict__ W1 = g ? (sW + 4096) : sW;
            const float* __restrict__ U1 = g ? (sU + 1024) : sU;
            const float* __restrict__ Wh = sW + 8192;
            vfloat2 gAcc = { sB[g * 32 + s], 0.f };
            vfloat2 hAcc = { 0.f, 0.f };
            #pragma unroll
            for (int e = 0; e < E; ++e) {
                const float src  = (e < 2) ? acc0 : acc1;
                const int   base = (e & 1) * 32;
                const float* w1c = W1 + e * 1024 + s * 2;
                const float* whc = Wh + e * 1024 + s * 2;
                #pragma unroll
                for (int k2 = 0; k2 < 16; ++k2) {
                    vfloat2 a2 = { rl(src, base + 2 * k2), rl(src, base + 2 * k2 + 1) };
                    vfloat2 w2 = *(const vfloat2*)(w1c + k2 * 64);   // ds_read_b64
                    vfloat2 h2 = *(const vfloat2*)(whc + k2 * 64);
                    gAcc = vfma2(a2, w2, gAcc);                      // v_pk_fma_f32
                    hAcc = vfma2(a2, h2, hAcc);
                }
            }
            {
                const float* u1c = U1 + s * 2;
                #pragma unroll
                for (int k2 = 0; k2 < 16; ++k2) {
                    vfloat2 a2 = { rl(hval, 2 * k2), rl(hval, 2 * k2 + 1) };
                    vfloat2 u2 = *(const vfloat2*)(u1c + k2 * 64);
                    gAcc = vfma2(a2, u2, gAcc);
                }
            }
            const float zr  = fast_sigmoid(gAcc.x + gAcc.y);   // z (g=0) | r (g=1)
            const float r_s = __shfl(zr, 32 + s, 64);
            const float z_s = __shfl(zr, s, 64);
            const float rh  = r_s * hval;
            {
                const float* uhc = sU + 2048 + s * 2;
                #pragma unroll
                for (int k2 = 0; k2 < 16; ++k2) {
                    vfloat2 a2 = { rl(rh, 2 * k2), rl(rh, 2 * k2 + 1) };
                    vfloat2 u2 = *(const vfloat2*)(uhc + k2 * 64);
                    hAcc = vfma2(a2, u2, hAcc);
                }
            }
            const float hh   = fast_tanh(hAcc.x + hAcc.y);
            const float hnew = fmaf(z_s, hval - hh, hh);       // z*h + (1-z)*hh
            if (g == 0) st_dev(&hn[n * S + s], hnew);
            hval = hnew;                                       // identical in both halves

            const float* t = hp; hp = hn; hn = (float*)t;      // swap

            if (l != 2 || it != 4) {                           // no barrier after last iter
                gbar(p.bar, phase, b); phase++;
            }
        }
    }

    // ---- epilogue in-register: node 5 = block 0, wave 5 (hval holds final h)
    if (b == 0 && wid == 5) {
        float y[5];
        #pragma unroll
        for (int j = 0; j < 5; ++j) y[j] = hval * p.ow[s * 5 + j];
        #pragma unroll
        for (int off = 1; off < 32; off <<= 1) {
            #pragma unroll
            for (int j = 0; j < 5; ++j) y[j] += __shfl_xor(y[j], off, 64);
        }
        #pragma unroll
        for (int j = 0; j < 5; ++j) y[j] += p.ob[j];
        float m = -1e30f;
        #pragma unroll
        for (int j = 0; j < 5; ++j) m = fmaxf(m, y[j]);
        float ssum = 0.f;
        #pragma unroll
        for (int j = 0; j < 5; ++j) ssum += __expf(y[j] - m);
        float lse = m + __logf(ssum);
        #pragma unroll
        for (int j = 0; j < 5; ++j) if (lane == j) p.out[j] = y[j] - lse;
    }
}

// ---------------------------------------------------------------------------
// Fallback chain — host launches it only if hipLaunchCooperativeKernel reports
// a synchronous rejection. Known-good round-3/5 structure.
// ---------------------------------------------------------------------------
__global__ __launch_bounds__(256) void init_h_fb(const float* __restrict__ x,
                                                 const float* __restrict__ fcw,
                                                 const float* __restrict__ fcb,
                                                 float* __restrict__ h0) {
    int t = blockIdx.x * 256 + threadIdx.x;
    int s = t & 31;
    int n = t >> 5;
    float acc = fcb[s];
    #pragma unroll 8
    for (int k = 0; k < FIN; ++k)
        acc = fmaf(x[n * FIN + k], fcw[k * S + s], acc);
    h0[n * S + s] = acc;
}

__global__ __launch_bounds__(512) void ggnn_iter_fb(
    const float* __restrict__ hprev, float* __restrict__ hnext,
    const int* __restrict__ deg, const int* __restrict__ csr,
    const float* __restrict__ wz, const float* __restrict__ wr, const float* __restrict__ wh,
    const float* __restrict__ uz, const float* __restrict__ ur, const float* __restrict__ uh,
    const float* __restrict__ bz, const float* __restrict__ br) {
    __shared__ __align__(16) float sWz[4096];
    __shared__ __align__(16) float sWr[4096];
    __shared__ __align__(16) float sWh[4096];
    __shared__ __align__(16) float sUz[1024], sUr[1024], sUh[1024];

    int tid = threadIdx.x;
    {
        float4*       dz = (float4*)sWz; const float4* gz = (const float4*)wz;
        float4*       dr = (float4*)sWr; const float4* gr = (const float4*)wr;
        float4*       dh = (float4*)sWh; const float4* gh = (const float4*)wh;
        for (int i = tid; i < 1024; i += 512) { dz[i] = gz[i]; dr[i] = gr[i]; dh[i] = gh[i]; }
        float4*       duz = (float4*)sUz; const float4* guz = (const float4*)uz;
        float4*       dur = (float4*)sUr; const float4* gur = (const float4*)ur;
        float4*       duh = (float4*)sUh; const float4* guh = (const float4*)uh;
        if (tid < 256) { duz[tid] = guz[tid]; dur[tid] = gur[tid]; duh[tid] = guh[tid]; }
    }
    __syncthreads();

    const int wid  = tid >> 6;
    const int lane = tid & 63;
    const int s    = lane & 31;
    const int g    = lane >> 5;
    const int n    = blockIdx.x * 8 + wid;

    const int d1 = min(deg[g * N + n], CAP);
    const int d2 = min(deg[(g + 2) * N + n], CAP);
    const int* __restrict__ l1 = csr + (g * N + n) * CAP;
    const int* __restrict__ l2 = csr + ((g + 2) * N + n) * CAP;
    float acc0 = 0.f, acc1 = 0.f;
    const int dmax = max(d1, d2);
    for (int i = 0; i < dmax; ++i) {
        if (i < d1) acc0 += hprev[l1[i] * S + s];
        if (i < d2) acc1 += hprev[l2[i] * S + s];
    }
    const float hval = hprev[n * S + s];

    const float* __restrict__ W1 = g ? sWr : sWz;
    const float* __restrict__ U1 = g ? sUr : sUz;
    float accA = g ? br[s] : bz[s];
    float accB = 0.f;
    float hA = 0.f, hB = 0.f;
    #pragma unroll
    for (int e = 0; e < E; ++e) {
        const float src = (e < 2) ? acc0 : acc1;
        const float* w1c = W1 + e * 1024 + s;
        const float* whc = sWh + e * 1024 + s;
        #pragma unroll
        for (int k = 0; k < 32; k += 2) {
            float a0 = rl(src, (e & 1) * 32 + k);
            float a1 = rl(src, (e & 1) * 32 + k + 1);
            accA = fmaf(a0, w1c[(k)     * 32], accA);
            accB = fmaf(a1, w1c[(k + 1) * 32], accB);
            hA   = fmaf(a0, whc[(k)     * 32], hA);
            hB   = fmaf(a1, whc[(k + 1) * 32], hB);
        }
    }
    #pragma unroll
    for (int k = 0; k < 32; k += 2) {
        accA = fmaf(rl(hval, k),     U1[(k)     * 32 + s], accA);
        accB = fmaf(rl(hval, k + 1), U1[(k + 1) * 32 + s], accB);
    }
    const float zr  = fast_sigmoid(accA + accB);
    const float r_s = __shfl(zr, 32 + s, 64);
    const float z_s = __shfl(zr, s, 64);
    const float rh  = r_s * hval;
    #pragma unroll
    for (int k = 0; k < 32; k += 2) {
        hA = fmaf(rl(rh, k),     sUh[(k)     * 32 + s], hA);
        hB = fmaf(rl(rh, k + 1), sUh[(k + 1) * 32 + s], hB);
    }
    const float hh = fast_tanh(hA + hB);
    const float hnew = fmaf(z_s, hval - hh, hh);
    if (g == 0) hnext[n * S + s] = hnew;
}

__global__ void epilogue_fb(const float* __restrict__ h,
                            const float* __restrict__ ow, const float* __restrict__ ob,
                            float* __restrict__ out) {
    int lane = threadIdx.x;
    float y = 0.f;
    if (lane < 5) {
        y = ob[lane];
        for (int k = 0; k < 32; ++k)
            y = fmaf(h[5 * S + k], ow[k * 5 + lane], y);
    }
    float m = -1e30f;
    #pragma unroll
    for (int j = 0; j < 5; ++j) m = fmaxf(m, __shfl(y, j, 64));
    float ssum = 0.f;
    #pragma unroll
    for (int j = 0; j < 5; ++j) ssum += __expf(__shfl(y, j, 64) - m);
    float lse = m + __logf(ssum);
    if (lane < 5) out[lane] = y - lse;
}

extern "C" void kernel_launch(void* const* d_in, const int* in_sizes, int n_in,
                              void* d_out, int out_size, void* d_ws, size_t ws_size,
                              hipStream_t stream) {
    const float* x     = (const float*)d_in[0];
    // d_in[1] = x_lengths (int32) — unused by the reference
    const float* edges = (const float*)d_in[2];
    const float* fcw   = (const float*)d_in[3];
    const float* fcb   = (const float*)d_in[4];
    const float* wz    = (const float*)d_in[5];
    const float* wr    = (const float*)d_in[6];
    const float* wh    = (const float*)d_in[7];
    const float* uz    = (const float*)d_in[8];
    const float* ur    = (const float*)d_in[9];
    const float* uh    = (const float*)d_in[10];
    const float* bz    = (const float*)d_in[11];
    const float* br    = (const float*)d_in[12];
    const float* ow    = (const float*)d_in[13];
    const float* ob    = (const float*)d_in[14];

    char* ws = (char*)d_ws;
    float* h0  = (float*)(ws);                   // 3073 rows * 32 * 4 = 393,344 B
    float* h1  = (float*)(ws + 393600);
    int*   deg = (int*)(ws + 787200);            // 49,152 B
    int*   bar = (int*)(ws + 836352);            // 2,048 B tree-barrier lines
    int*   csr = (int*)(ws + 838400);            // 3,145,728 B -> end 3,984,128

    hipMemsetAsync(deg, 0, 49152 + 2048, stream);
    build_csr<<<256, 256, 0, stream>>>(edges, deg, csr);

    Params p;
    p.x = x; p.fcw = fcw; p.fcb = fcb;
    p.wz = wz; p.wr = wr; p.wh = wh;
    p.uz = uz; p.ur = ur; p.uh = uh;
    p.bz = bz; p.br = br; p.ow = ow; p.ob = ob;
    p.deg = deg; p.csr = csr; p.bar = bar;
    p.h0 = h0; p.h1 = h1; p.out = (float*)d_out;

    void* args[] = { &p };
    hipError_t err = hipLaunchCooperativeKernel((const void*)fused_ggnn,
                                                dim3(BLK), dim3(TPB), args, 0, stream);
    if (err != hipSuccess) {
        // Launch rejected synchronously -> known-good multi-dispatch path.
        init_h_fb<<<384, 256, 0, stream>>>(x, fcw, fcb, h0);
        float* ha = h0;
        float* hb = h1;
        for (int l = 0; l < 3; ++l) {
            for (int it = 0; it < 5; ++it) {
                ggnn_iter_fb<<<384, 512, 0, stream>>>(ha, hb, deg, csr,
                    wz + l * 4096, wr + l * 4096, wh + l * 4096,
                    uz + l * 1024, ur + l * 1024, uh + l * 1024,
                    bz + l * 32, br + l * 32);
                float* t = ha; ha = hb; hb = t;
            }
        }
        epilogue_fb<<<1, 64, 0, stream>>>(ha, ow, ob, (float*)d_out);
    }
}

// Round 12
// 454.671 us; speedup vs baseline: 1.2801x; 1.2801x over previous
//
#include <hip/hip_runtime.h>

constexpr int N     = 3072;
constexpr int S     = 32;
constexpr int E     = 4;
constexpr int FIN   = 64;
constexpr int CAP   = 64;     // max sources per (e,n); Binomial(3072,0.005) mean 15.4, P(>=64)~1e-19
constexpr int NNi   = N * N;  // 9,437,184
constexpr int DUMMY = N;      // extra all-zero h row for gather padding
constexpr int BLK   = 256;    // 1 block/CU
constexpr int TPB   = 768;    // 12 waves = 12 nodes per block; 256*12 = 3072
constexpr int NPB   = 12;

typedef float vfloat2 __attribute__((ext_vector_type(2)));

__device__ __forceinline__ vfloat2 vfma2(vfloat2 a, vfloat2 b, vfloat2 c) {
#if __has_builtin(__builtin_elementwise_fma)
    return __builtin_elementwise_fma(a, b, c);   // lowers to v_pk_fma_f32
#else
    vfloat2 r; r.x = fmaf(a.x, b.x, c.x); r.y = fmaf(a.y, b.y, c.y); return r;
#endif
}

__device__ __forceinline__ float rl(float v, int lane) {   // wave-uniform broadcast via VALU
    return __int_as_float(__builtin_amdgcn_readlane(__float_as_int(v), lane));
}
__device__ __forceinline__ float fast_sigmoid(float x) {
    x = fminf(fmaxf(x, -30.f), 30.f);
    return 1.f / (1.f + __expf(-x));
}
__device__ __forceinline__ float fast_tanh(float x) {
    x = fminf(fmaxf(x, -15.f), 15.f);
    float e = __expf(2.f * x);
    return (e - 1.f) / (e + 1.f);
}

// Cache-bypassing accessors: relaxed AGENT-scope atomics are coherent at the
// memory-side Infinity Cache (above the non-coherent per-XCD L2s).
__device__ __forceinline__ float ld_dev(const float* p) {
    return __hip_atomic_load((float*)p, __ATOMIC_RELAXED, __HIP_MEMORY_SCOPE_AGENT);
}
__device__ __forceinline__ void st_dev(float* p, float v) {
    __hip_atomic_store(p, v, __ATOMIC_RELAXED, __HIP_MEMORY_SCOPE_AGENT);
}

// Two-level monotone tree barrier (reset-free), 16 groups x 16 blocks.
__device__ __forceinline__ void gbar(int* bar, int ph, int b) {
    __syncthreads();          // compiler drains vmcnt(0) before s_barrier
    if (threadIdx.x == 0) {
        int* grp  = bar + (b >> 4) * 16;
        int* root = bar + 256;
        int* go   = bar + 272;
        int old = __hip_atomic_fetch_add(grp, 1, __ATOMIC_RELAXED, __HIP_MEMORY_SCOPE_AGENT);
        if (old + 1 == ph * 16) {
            int old2 = __hip_atomic_fetch_add(root, 1, __ATOMIC_RELAXED, __HIP_MEMORY_SCOPE_AGENT);
            if (old2 + 1 == ph * 16)
                __hip_atomic_store(go, ph, __ATOMIC_RELAXED, __HIP_MEMORY_SCOPE_AGENT);
        }
        int spins = 0;
        while (__hip_atomic_load(go, __ATOMIC_RELAXED, __HIP_MEMORY_SCOPE_AGENT) < ph) {
            __builtin_amdgcn_s_sleep(2);
            if (++spins > 300000) break;           // wedge -> terminate, not hang
        }
    }
    __syncthreads();
}

// ---------------------------------------------------------------------------
// Pass 1: dense fp32 adjacency -> CSR. One thread per float4 (9.4M threads):
// maximal memory-level parallelism — the grid-stride variant (round 11)
// exposed HBM latency and cost ~130 µs. ~92% of threads exit on the zero test.
// ---------------------------------------------------------------------------
__global__ __launch_bounds__(256) void build_csr(const float* __restrict__ edges,
                                                 int* __restrict__ deg,
                                                 int* __restrict__ csr) {
    int t = blockIdx.x * 256 + threadIdx.x;
    int idx4 = t * 4;
    float4 v = *reinterpret_cast<const float4*>(edges + idx4);
    if (v.x == 0.f && v.y == 0.f && v.z == 0.f && v.w == 0.f) return;
    int e   = idx4 / NNi;
    int rem = idx4 - e * NNi;
    int m   = rem / N;
    int nb  = rem - m * N;
    float w[4] = {v.x, v.y, v.z, v.w};
    int base = e * N + nb;
    #pragma unroll
    for (int j = 0; j < 4; ++j) {
        if (w[j] != 0.f) {
            int slot = base + j;
            int pos = atomicAdd(&deg[slot], 1);
            if (pos < CAP) csr[slot * CAP + pos] = m;
        }
    }
}

struct Params {
    const float *x, *fcw, *fcb;
    const float *wz, *wr, *wh, *uz, *ur, *uh, *bz, *br;
    const float *ow, *ob;
    const int   *deg, *csr;
    int   *bar;
    float *h0, *h1, *out;
};

// ---------------------------------------------------------------------------
// Fused cooperative kernel: round-8 structure + packed-pair weight layout.
// LDS W layout: [mat][e][k2][s][2] (k-pairs adjacent) -> ds_read_b64 +
// v_pk_fma_f32 per k-pair: halves LDS instructions and FMA issue count.
// One wave per node; lane = (g,s); half g handles edge types {g, g+2} in the
// gather and the z (g=0) / r (g=1) gate.
// ---------------------------------------------------------------------------
__global__ __launch_bounds__(TPB, 3) void fused_ggnn(Params p) {
    __shared__ __align__(16) float sW[3 * 4096];   // [z|r|h][e][k2][s][2]
    __shared__ __align__(16) float sU[3 * 1024];   // [z|r|h][k2][s][2]
    __shared__ float sB[64];                       // [bz|br][s]

    const int tid  = threadIdx.x;
    const int b    = blockIdx.x;
    const int wid  = tid >> 6;
    const int lane = tid & 63;
    const int s    = lane & 31;
    const int g    = lane >> 5;
    const int n    = b * NPB + wid;

    // ---- init: h0 = x @ fc_w + fc_b, redundantly in both halves so hval
    // lives in a register for the whole kernel; store once (g==0).
    float hval;
    {
        float acc = p.fcb[s];
        #pragma unroll 8
        for (int k = 0; k < FIN; ++k)
            acc = fmaf(p.x[n * FIN + k], p.fcw[k * S + s], acc);
        hval = acc;
        if (g == 0) st_dev(&p.h0[n * S + s], acc);
    }
    if (b == 0) {                                  // zero dummy rows, both buffers
        if (tid < 32)      st_dev(&p.h0[DUMMY * S + tid], 0.f);
        else if (tid < 64) st_dev(&p.h1[DUMMY * S + (tid - 32)], 0.f);
    }

    // ---- iteration-invariant CSR state (prev-dispatch data: cached reads OK)
    const int slot1 = g * N + n;
    const int slot2 = (g + 2) * N + n;
    const int d1 = min(p.deg[slot1], CAP);
    const int d2 = min(p.deg[slot2], CAP);
    const int* __restrict__ l1 = p.csr + slot1 * CAP;
    const int* __restrict__ l2 = p.csr + slot2 * CAP;
    const int dm = max(d1, d2);

    const float* hp = p.h0;
    float*       hn = p.h1;
    int phase = 1;
    gbar(p.bar, phase, b); phase++;                // h0 device-visible

    for (int l = 0; l < 3; ++l) {
        __syncthreads();                           // guard LDS reuse across layers
        {
            // W: 3 mats x 2048 float2; pair k/k+1 into adjacent floats.
            const float* gsrc[3] = { p.wz + l * 4096, p.wr + l * 4096, p.wh + l * 4096 };
            for (int j = tid; j < 6144; j += TPB) {
                int mat = j >> 11;                 // /2048
                int r   = j & 2047;
                int e   = r >> 9;                  // 512 float2 per e
                int rr  = r & 511;
                int k2  = rr >> 5;
                int ss  = rr & 31;
                const float* src = gsrc[mat] + e * 1024 + (2 * k2) * 32 + ss;
                float2 val = { src[0], src[32] };
                *(float2*)(sW + mat * 4096 + e * 1024 + k2 * 64 + ss * 2) = val;
            }
            // U: 3 mats x 512 float2
            const float* usrc[3] = { p.uz + l * 1024, p.ur + l * 1024, p.uh + l * 1024 };
            for (int j = tid; j < 1536; j += TPB) {
                int mat = j >> 9;
                int rr  = j & 511;
                int k2  = rr >> 5;
                int ss  = rr & 31;
                const float* src = usrc[mat] + (2 * k2) * 32 + ss;
                float2 val = { src[0], src[32] };
                *(float2*)(sU + mat * 1024 + k2 * 64 + ss * 2) = val;
            }
            if (tid < 64) sB[tid] = (tid < 32) ? p.bz[l * 32 + tid]
                                               : p.br[l * 32 + (tid - 32)];
        }
        __syncthreads();

        for (int it = 0; it < 5; ++it) {
            // ---- phase A: sparse gather (round-8 chunk-4, proven)
            float acc0 = 0.f, acc1 = 0.f;
            for (int c = 0; c < dm; c += 4) {
                int4 ia = *reinterpret_cast<const int4*>(l1 + c);
                int4 ib = *reinterpret_cast<const int4*>(l2 + c);
                int r0 = (c + 0 < d1) ? ia.x : DUMMY;
                int r1 = (c + 1 < d1) ? ia.y : DUMMY;
                int r2 = (c + 2 < d1) ? ia.z : DUMMY;
                int r3 = (c + 3 < d1) ? ia.w : DUMMY;
                int q0 = (c + 0 < d2) ? ib.x : DUMMY;
                int q1 = (c + 1 < d2) ? ib.y : DUMMY;
                int q2 = (c + 2 < d2) ? ib.z : DUMMY;
                int q3 = (c + 3 < d2) ? ib.w : DUMMY;
                float v0 = ld_dev(hp + r0 * S + s), v1 = ld_dev(hp + r1 * S + s);
                float v2 = ld_dev(hp + r2 * S + s), v3 = ld_dev(hp + r3 * S + s);
                float u0 = ld_dev(hp + q0 * S + s), u1 = ld_dev(hp + q1 * S + s);
                float u2 = ld_dev(hp + q2 * S + s), u3 = ld_dev(hp + q3 * S + s);
                acc0 += (v0 + v1) + (v2 + v3);
                acc1 += (u0 + u1) + (u2 + u3);
            }

            // ---- phases B+C: z|r gate (split halves) + hh, packed-pair math
            const float* __restrict__ W1 = g ? (sW + 4096) : sW;
            const float* __restrict__ U1 = g ? (sU + 1024) : sU;
            const float* __restrict__ Wh = sW + 8192;
            vfloat2 gAcc = { sB[g * 32 + s], 0.f };
            vfloat2 hAcc = { 0.f, 0.f };
            #pragma unroll
            for (int e = 0; e < E; ++e) {
                const float src  = (e < 2) ? acc0 : acc1;
                const int   base = (e & 1) * 32;
                const float* w1c = W1 + e * 1024 + s * 2;
                const float* whc = Wh + e * 1024 + s * 2;
                #pragma unroll
                for (int k2 = 0; k2 < 16; ++k2) {
                    vfloat2 a2 = { rl(src, base + 2 * k2), rl(src, base + 2 * k2 + 1) };
                    vfloat2 w2 = *(const vfloat2*)(w1c + k2 * 64);   // ds_read_b64
                    vfloat2 h2 = *(const vfloat2*)(whc + k2 * 64);
                    gAcc = vfma2(a2, w2, gAcc);                      // v_pk_fma_f32
                    hAcc = vfma2(a2, h2, hAcc);
                }
            }
            {
                const float* u1c = U1 + s * 2;
                #pragma unroll
                for (int k2 = 0; k2 < 16; ++k2) {
                    vfloat2 a2 = { rl(hval, 2 * k2), rl(hval, 2 * k2 + 1) };
                    vfloat2 u2 = *(const vfloat2*)(u1c + k2 * 64);
                    gAcc = vfma2(a2, u2, gAcc);
                }
            }
            const float zr  = fast_sigmoid(gAcc.x + gAcc.y);   // z (g=0) | r (g=1)
            const float r_s = __shfl(zr, 32 + s, 64);
            const float z_s = __shfl(zr, s, 64);
            const float rh  = r_s * hval;
            {
                const float* uhc = sU + 2048 + s * 2;
                #pragma unroll
                for (int k2 = 0; k2 < 16; ++k2) {
                    vfloat2 a2 = { rl(rh, 2 * k2), rl(rh, 2 * k2 + 1) };
                    vfloat2 u2 = *(const vfloat2*)(uhc + k2 * 64);
                    hAcc = vfma2(a2, u2, hAcc);
                }
            }
            const float hh   = fast_tanh(hAcc.x + hAcc.y);
            const float hnew = fmaf(z_s, hval - hh, hh);       // z*h + (1-z)*hh
            if (g == 0) st_dev(&hn[n * S + s], hnew);
            hval = hnew;                                       // identical in both halves

            const float* t = hp; hp = hn; hn = (float*)t;      // swap

            if (l != 2 || it != 4) {                           // no barrier after last iter
                gbar(p.bar, phase, b); phase++;
            }
        }
    }

    // ---- epilogue in-register: node 5 = block 0, wave 5 (hval holds final h)
    if (b == 0 && wid == 5) {
        float y[5];
        #pragma unroll
        for (int j = 0; j < 5; ++j) y[j] = hval * p.ow[s * 5 + j];
        #pragma unroll
        for (int off = 1; off < 32; off <<= 1) {
            #pragma unroll
            for (int j = 0; j < 5; ++j) y[j] += __shfl_xor(y[j], off, 64);
        }
        #pragma unroll
        for (int j = 0; j < 5; ++j) y[j] += p.ob[j];
        float m = -1e30f;
        #pragma unroll
        for (int j = 0; j < 5; ++j) m = fmaxf(m, y[j]);
        float ssum = 0.f;
        #pragma unroll
        for (int j = 0; j < 5; ++j) ssum += __expf(y[j] - m);
        float lse = m + __logf(ssum);
        #pragma unroll
        for (int j = 0; j < 5; ++j) if (lane == j) p.out[j] = y[j] - lse;
    }
}

// ---------------------------------------------------------------------------
// Fallback chain — host launches it only if hipLaunchCooperativeKernel reports
// a synchronous rejection. Known-good round-3/5 structure.
// ---------------------------------------------------------------------------
__global__ __launch_bounds__(256) void init_h_fb(const float* __restrict__ x,
                                                 const float* __restrict__ fcw,
                                                 const float* __restrict__ fcb,
                                                 float* __restrict__ h0) {
    int t = blockIdx.x * 256 + threadIdx.x;
    int s = t & 31;
    int n = t >> 5;
    float acc = fcb[s];
    #pragma unroll 8
    for (int k = 0; k < FIN; ++k)
        acc = fmaf(x[n * FIN + k], fcw[k * S + s], acc);
    h0[n * S + s] = acc;
}

__global__ __launch_bounds__(512) void ggnn_iter_fb(
    const float* __restrict__ hprev, float* __restrict__ hnext,
    const int* __restrict__ deg, const int* __restrict__ csr,
    const float* __restrict__ wz, const float* __restrict__ wr, const float* __restrict__ wh,
    const float* __restrict__ uz, const float* __restrict__ ur, const float* __restrict__ uh,
    const float* __restrict__ bz, const float* __restrict__ br) {
    __shared__ __align__(16) float sWz[4096];
    __shared__ __align__(16) float sWr[4096];
    __shared__ __align__(16) float sWh[4096];
    __shared__ __align__(16) float sUz[1024], sUr[1024], sUh[1024];

    int tid = threadIdx.x;
    {
        float4*       dz = (float4*)sWz; const float4* gz = (const float4*)wz;
        float4*       dr = (float4*)sWr; const float4* gr = (const float4*)wr;
        float4*       dh = (float4*)sWh; const float4* gh = (const float4*)wh;
        for (int i = tid; i < 1024; i += 512) { dz[i] = gz[i]; dr[i] = gr[i]; dh[i] = gh[i]; }
        float4*       duz = (float4*)sUz; const float4* guz = (const float4*)uz;
        float4*       dur = (float4*)sUr; const float4* gur = (const float4*)ur;
        float4*       duh = (float4*)sUh; const float4* guh = (const float4*)uh;
        if (tid < 256) { duz[tid] = guz[tid]; dur[tid] = gur[tid]; duh[tid] = guh[tid]; }
    }
    __syncthreads();

    const int wid  = tid >> 6;
    const int lane = tid & 63;
    const int s    = lane & 31;
    const int g    = lane >> 5;
    const int n    = blockIdx.x * 8 + wid;

    const int d1 = min(deg[g * N + n], CAP);
    const int d2 = min(deg[(g + 2) * N + n], CAP);
    const int* __restrict__ l1 = csr + (g * N + n) * CAP;
    const int* __restrict__ l2 = csr + ((g + 2) * N + n) * CAP;
    float acc0 = 0.f, acc1 = 0.f;
    const int dmax = max(d1, d2);
    for (int i = 0; i < dmax; ++i) {
        if (i < d1) acc0 += hprev[l1[i] * S + s];
        if (i < d2) acc1 += hprev[l2[i] * S + s];
    }
    const float hval = hprev[n * S + s];

    const float* __restrict__ W1 = g ? sWr : sWz;
    const float* __restrict__ U1 = g ? sUr : sUz;
    float accA = g ? br[s] : bz[s];
    float accB = 0.f;
    float hA = 0.f, hB = 0.f;
    #pragma unroll
    for (int e = 0; e < E; ++e) {
        const float src = (e < 2) ? acc0 : acc1;
        const float* w1c = W1 + e * 1024 + s;
        const float* whc = sWh + e * 1024 + s;
        #pragma unroll
        for (int k = 0; k < 32; k += 2) {
            float a0 = rl(src, (e & 1) * 32 + k);
            float a1 = rl(src, (e & 1) * 32 + k + 1);
            accA = fmaf(a0, w1c[(k)     * 32], accA);
            accB = fmaf(a1, w1c[(k + 1) * 32], accB);
            hA   = fmaf(a0, whc[(k)     * 32], hA);
            hB   = fmaf(a1, whc[(k + 1) * 32], hB);
        }
    }
    #pragma unroll
    for (int k = 0; k < 32; k += 2) {
        accA = fmaf(rl(hval, k),     U1[(k)     * 32 + s], accA);
        accB = fmaf(rl(hval, k + 1), U1[(k + 1) * 32 + s], accB);
    }
    const float zr  = fast_sigmoid(accA + accB);
    const float r_s = __shfl(zr, 32 + s, 64);
    const float z_s = __shfl(zr, s, 64);
    const float rh  = r_s * hval;
    #pragma unroll
    for (int k = 0; k < 32; k += 2) {
        hA = fmaf(rl(rh, k),     sUh[(k)     * 32 + s], hA);
        hB = fmaf(rl(rh, k + 1), sUh[(k + 1) * 32 + s], hB);
    }
    const float hh = fast_tanh(hA + hB);
    const float hnew = fmaf(z_s, hval - hh, hh);
    if (g == 0) hnext[n * S + s] = hnew;
}

__global__ void epilogue_fb(const float* __restrict__ h,
                            const float* __restrict__ ow, const float* __restrict__ ob,
                            float* __restrict__ out) {
    int lane = threadIdx.x;
    float y = 0.f;
    if (lane < 5) {
        y = ob[lane];
        for (int k = 0; k < 32; ++k)
            y = fmaf(h[5 * S + k], ow[k * 5 + lane], y);
    }
    float m = -1e30f;
    #pragma unroll
    for (int j = 0; j < 5; ++j) m = fmaxf(m, __shfl(y, j, 64));
    float ssum = 0.f;
    #pragma unroll
    for (int j = 0; j < 5; ++j) ssum += __expf(__shfl(y, j, 64) - m);
    float lse = m + __logf(ssum);
    if (lane < 5) out[lane] = y - lse;
}

extern "C" void kernel_launch(void* const* d_in, const int* in_sizes, int n_in,
                              void* d_out, int out_size, void* d_ws, size_t ws_size,
                              hipStream_t stream) {
    const float* x     = (const float*)d_in[0];
    // d_in[1] = x_lengths (int32) — unused by the reference
    const float* edges = (const float*)d_in[2];
    const float* fcw   = (const float*)d_in[3];
    const float* fcb   = (const float*)d_in[4];
    const float* wz    = (const float*)d_in[5];
    const float* wr    = (const float*)d_in[6];
    const float* wh    = (const float*)d_in[7];
    const float* uz    = (const float*)d_in[8];
    const float* ur    = (const float*)d_in[9];
    const float* uh    = (const float*)d_in[10];
    const float* bz    = (const float*)d_in[11];
    const float* br    = (const float*)d_in[12];
    const float* ow    = (const float*)d_in[13];
    const float* ob    = (const float*)d_in[14];

    char* ws = (char*)d_ws;
    float* h0  = (float*)(ws);                   // 3073 rows * 32 * 4 = 393,344 B
    float* h1  = (float*)(ws + 393600);
    int*   deg = (int*)(ws + 787200);            // 49,152 B
    int*   bar = (int*)(ws + 836352);            // 2,048 B tree-barrier lines
    int*   csr = (int*)(ws + 838400);            // 3,145,728 B -> end 3,984,128

    hipMemsetAsync(deg, 0, 49152 + 2048, stream);
    build_csr<<<36864, 256, 0, stream>>>(edges, deg, csr);

    Params p;
    p.x = x; p.fcw = fcw; p.fcb = fcb;
    p.wz = wz; p.wr = wr; p.wh = wh;
    p.uz = uz; p.ur = ur; p.uh = uh;
    p.bz = bz; p.br = br; p.ow = ow; p.ob = ob;
    p.deg = deg; p.csr = csr; p.bar = bar;
    p.h0 = h0; p.h1 = h1; p.out = (float*)d_out;

    void* args[] = { &p };
    hipError_t err = hipLaunchCooperativeKernel((const void*)fused_ggnn,
                                                dim3(BLK), dim3(TPB), args, 0, stream);
    if (err != hipSuccess) {
        // Launch rejected synchronously -> known-good multi-dispatch path.
        init_h_fb<<<384, 256, 0, stream>>>(x, fcw, fcb, h0);
        float* ha = h0;
        float* hb = h1;
        for (int l = 0; l < 3; ++l) {
            for (int it = 0; it < 5; ++it) {
                ggnn_iter_fb<<<384, 512, 0, stream>>>(ha, hb, deg, csr,
                    wz + l * 4096, wr + l * 4096, wh + l * 4096,
                    uz + l * 1024, ur + l * 1024, uh + l * 1024,
                    bz + l * 32, br + l * 32);
                float* t = ha; ha = hb; hb = t;
            }
        }
        epilogue_fb<<<1, 64, 0, stream>>>(ha, ow, ob, (float*)d_out);
    }
}

// Round 13
// 447.480 us; speedup vs baseline: 1.3006x; 1.0161x over previous
//
#include <hip/hip_runtime.h>

constexpr int N     = 3072;
constexpr int S     = 32;
constexpr int E     = 4;
constexpr int FIN   = 64;
constexpr int CAP   = 64;     // max sources per (e,n); Binomial(3072,0.005) mean 15.4, P(>=64)~1e-19
constexpr int NNi   = N * N;  // 9,437,184
constexpr int DUMMY = N;      // extra all-zero h row for gather padding
constexpr int BLK   = 256;    // 1 block/CU
constexpr int TPB   = 768;    // 12 waves = 12 nodes per block; 256*12 = 3072
constexpr int NPB   = 12;

typedef float vfloat2 __attribute__((ext_vector_type(2)));

__device__ __forceinline__ vfloat2 vfma2(vfloat2 a, vfloat2 b, vfloat2 c) {
#if __has_builtin(__builtin_elementwise_fma)
    return __builtin_elementwise_fma(a, b, c);   // lowers to v_pk_fma_f32
#else
    vfloat2 r; r.x = fmaf(a.x, b.x, c.x); r.y = fmaf(a.y, b.y, c.y); return r;
#endif
}

__device__ __forceinline__ float rl(float v, int lane) {   // wave-uniform broadcast via VALU
    return __int_as_float(__builtin_amdgcn_readlane(__float_as_int(v), lane));
}
__device__ __forceinline__ float fast_sigmoid(float x) {
    x = fminf(fmaxf(x, -30.f), 30.f);
    return 1.f / (1.f + __expf(-x));
}
__device__ __forceinline__ float fast_tanh(float x) {
    x = fminf(fmaxf(x, -15.f), 15.f);
    float e = __expf(2.f * x);
    return (e - 1.f) / (e + 1.f);
}

// Cache-bypassing accessors: relaxed AGENT-scope atomics are coherent at the
// memory-side Infinity Cache (above the non-coherent per-XCD L2s).
__device__ __forceinline__ float ld_dev(const float* p) {
    return __hip_atomic_load((float*)p, __ATOMIC_RELAXED, __HIP_MEMORY_SCOPE_AGENT);
}
__device__ __forceinline__ void st_dev(float* p, float v) {
    __hip_atomic_store(p, v, __ATOMIC_RELAXED, __HIP_MEMORY_SCOPE_AGENT);
}

// Two-level monotone tree barrier (reset-free), 16 groups x 16 blocks.
// bar layout (ints, 64B-line granularity):
//   [gi*16]        : per-group arrival counters (16 lines)
//   [256]          : root counter (group-last arrivers only)
//   [272 + gi*16]  : per-group release lines (fan-out: root-last writes all 16,
//                    so each line has only 16 pollers instead of 256)
// Spin is tight (no sleep quantization); s_sleep only every 1024 polls as a
// power/wedge guard.
__device__ __forceinline__ void gbar(int* bar, int ph, int b) {
    __syncthreads();          // compiler drains vmcnt(0) before s_barrier
    if (threadIdx.x == 0) {
        const int gi = b >> 4;
        int* grp  = bar + gi * 16;
        int* root = bar + 256;
        int* go   = bar + 272 + gi * 16;
        int old = __hip_atomic_fetch_add(grp, 1, __ATOMIC_RELAXED, __HIP_MEMORY_SCOPE_AGENT);
        if (old + 1 == ph * 16) {          // last of this group for phase ph
            int old2 = __hip_atomic_fetch_add(root, 1, __ATOMIC_RELAXED, __HIP_MEMORY_SCOPE_AGENT);
            if (old2 + 1 == ph * 16) {     // last group overall: fan-out release
                #pragma unroll
                for (int g2 = 0; g2 < 16; ++g2)
                    __hip_atomic_store(bar + 272 + g2 * 16, ph,
                                       __ATOMIC_RELAXED, __HIP_MEMORY_SCOPE_AGENT);
            }
        }
        int spins = 0;
        while (__hip_atomic_load(go, __ATOMIC_RELAXED, __HIP_MEMORY_SCOPE_AGENT) < ph) {
            if ((++spins & 1023) == 0) __builtin_amdgcn_s_sleep(1);
            if (spins > 30000000) break;   // wedge -> terminate, not hang
        }
    }
    __syncthreads();
}

// ---------------------------------------------------------------------------
// Pass 1: dense fp32 adjacency -> CSR. One thread per float4 (9.4M threads):
// maximal memory-level parallelism — at the 151 MB HBM-scan roofline (~25 µs).
// ~92% of threads exit on the zero test.
// ---------------------------------------------------------------------------
__global__ __launch_bounds__(256) void build_csr(const float* __restrict__ edges,
                                                 int* __restrict__ deg,
                                                 int* __restrict__ csr) {
    int t = blockIdx.x * 256 + threadIdx.x;
    int idx4 = t * 4;
    float4 v = *reinterpret_cast<const float4*>(edges + idx4);
    if (v.x == 0.f && v.y == 0.f && v.z == 0.f && v.w == 0.f) return;
    int e   = idx4 / NNi;
    int rem = idx4 - e * NNi;
    int m   = rem / N;
    int nb  = rem - m * N;
    float w[4] = {v.x, v.y, v.z, v.w};
    int base = e * N + nb;
    #pragma unroll
    for (int j = 0; j < 4; ++j) {
        if (w[j] != 0.f) {
            int slot = base + j;
            int pos = atomicAdd(&deg[slot], 1);
            if (pos < CAP) csr[slot * CAP + pos] = m;
        }
    }
}

struct Params {
    const float *x, *fcw, *fcb;
    const float *wz, *wr, *wh, *uz, *ur, *uh, *bz, *br;
    const float *ow, *ob;
    const int   *deg, *csr;
    int   *bar;
    float *h0, *h1, *out;
};

// ---------------------------------------------------------------------------
// Fused cooperative kernel: round-8 structure + packed-pair weight layout.
// LDS W layout: [mat][e][k2][s][2] (k-pairs adjacent) -> ds_read_b64 +
// v_pk_fma_f32 per k-pair. One wave per node; lane = (g,s); half g handles
// edge types {g, g+2} in the gather and the z (g=0) / r (g=1) gate.
// ---------------------------------------------------------------------------
__global__ __launch_bounds__(TPB, 3) void fused_ggnn(Params p) {
    __shared__ __align__(16) float sW[3 * 4096];   // [z|r|h][e][k2][s][2]
    __shared__ __align__(16) float sU[3 * 1024];   // [z|r|h][k2][s][2]
    __shared__ float sB[64];                       // [bz|br][s]

    const int tid  = threadIdx.x;
    const int b    = blockIdx.x;
    const int wid  = tid >> 6;
    const int lane = tid & 63;
    const int s    = lane & 31;
    const int g    = lane >> 5;
    const int n    = b * NPB + wid;

    // ---- init: h0 = x @ fc_w + fc_b, redundantly in both halves so hval
    // lives in a register for the whole kernel; store once (g==0).
    float hval;
    {
        float acc = p.fcb[s];
        #pragma unroll 8
        for (int k = 0; k < FIN; ++k)
            acc = fmaf(p.x[n * FIN + k], p.fcw[k * S + s], acc);
        hval = acc;
        if (g == 0) st_dev(&p.h0[n * S + s], acc);
    }
    if (b == 0) {                                  // zero dummy rows, both buffers
        if (tid < 32)      st_dev(&p.h0[DUMMY * S + tid], 0.f);
        else if (tid < 64) st_dev(&p.h1[DUMMY * S + (tid - 32)], 0.f);
    }

    // ---- iteration-invariant CSR state (prev-dispatch data: cached reads OK)
    const int slot1 = g * N + n;
    const int slot2 = (g + 2) * N + n;
    const int d1 = min(p.deg[slot1], CAP);
    const int d2 = min(p.deg[slot2], CAP);
    const int* __restrict__ l1 = p.csr + slot1 * CAP;
    const int* __restrict__ l2 = p.csr + slot2 * CAP;
    const int dm = max(d1, d2);

    const float* hp = p.h0;
    float*       hn = p.h1;
    int phase = 1;
    gbar(p.bar, phase, b); phase++;                // h0 device-visible

    for (int l = 0; l < 3; ++l) {
        __syncthreads();                           // guard LDS reuse across layers
        {
            // W: 3 mats x 2048 float2; pair k/k+1 into adjacent floats.
            const float* gsrc[3] = { p.wz + l * 4096, p.wr + l * 4096, p.wh + l * 4096 };
            for (int j = tid; j < 6144; j += TPB) {
                int mat = j >> 11;                 // /2048
                int r   = j & 2047;
                int e   = r >> 9;                  // 512 float2 per e
                int rr  = r & 511;
                int k2  = rr >> 5;
                int ss  = rr & 31;
                const float* src = gsrc[mat] + e * 1024 + (2 * k2) * 32 + ss;
                float2 val = { src[0], src[32] };
                *(float2*)(sW + mat * 4096 + e * 1024 + k2 * 64 + ss * 2) = val;
            }
            // U: 3 mats x 512 float2
            const float* usrc[3] = { p.uz + l * 1024, p.ur + l * 1024, p.uh + l * 1024 };
            for (int j = tid; j < 1536; j += TPB) {
                int mat = j >> 9;
                int rr  = j & 511;
                int k2  = rr >> 5;
                int ss  = rr & 31;
                const float* src = usrc[mat] + (2 * k2) * 32 + ss;
                float2 val = { src[0], src[32] };
                *(float2*)(sU + mat * 1024 + k2 * 64 + ss * 2) = val;
            }
            if (tid < 64) sB[tid] = (tid < 32) ? p.bz[l * 32 + tid]
                                               : p.br[l * 32 + (tid - 32)];
        }
        __syncthreads();

        for (int it = 0; it < 5; ++it) {
            // ---- phase A: sparse gather (round-8 chunk-4, proven)
            float acc0 = 0.f, acc1 = 0.f;
            for (int c = 0; c < dm; c += 4) {
                int4 ia = *reinterpret_cast<const int4*>(l1 + c);
                int4 ib = *reinterpret_cast<const int4*>(l2 + c);
                int r0 = (c + 0 < d1) ? ia.x : DUMMY;
                int r1 = (c + 1 < d1) ? ia.y : DUMMY;
                int r2 = (c + 2 < d1) ? ia.z : DUMMY;
                int r3 = (c + 3 < d1) ? ia.w : DUMMY;
                int q0 = (c + 0 < d2) ? ib.x : DUMMY;
                int q1 = (c + 1 < d2) ? ib.y : DUMMY;
                int q2 = (c + 2 < d2) ? ib.z : DUMMY;
                int q3 = (c + 3 < d2) ? ib.w : DUMMY;
                float v0 = ld_dev(hp + r0 * S + s), v1 = ld_dev(hp + r1 * S + s);
                float v2 = ld_dev(hp + r2 * S + s), v3 = ld_dev(hp + r3 * S + s);
                float u0 = ld_dev(hp + q0 * S + s), u1 = ld_dev(hp + q1 * S + s);
                float u2 = ld_dev(hp + q2 * S + s), u3 = ld_dev(hp + q3 * S + s);
                acc0 += (v0 + v1) + (v2 + v3);
                acc1 += (u0 + u1) + (u2 + u3);
            }

            // ---- phases B+C: z|r gate (split halves) + hh, packed-pair math
            const float* __restrict__ W1 = g ? (sW + 4096) : sW;
            const float* __restrict__ U1 = g ? (sU + 1024) : sU;
            const float* __restrict__ Wh = sW + 8192;
            vfloat2 gAcc = { sB[g * 32 + s], 0.f };
            vfloat2 hAcc = { 0.f, 0.f };
            #pragma unroll
            for (int e = 0; e < E; ++e) {
                const float src  = (e < 2) ? acc0 : acc1;
                const int   base = (e & 1) * 32;
                const float* w1c = W1 + e * 1024 + s * 2;
                const float* whc = Wh + e * 1024 + s * 2;
                #pragma unroll
                for (int k2 = 0; k2 < 16; ++k2) {
                    vfloat2 a2 = { rl(src, base + 2 * k2), rl(src, base + 2 * k2 + 1) };
                    vfloat2 w2 = *(const vfloat2*)(w1c + k2 * 64);   // ds_read_b64
                    vfloat2 h2 = *(const vfloat2*)(whc + k2 * 64);
                    gAcc = vfma2(a2, w2, gAcc);                      // v_pk_fma_f32
                    hAcc = vfma2(a2, h2, hAcc);
                }
            }
            {
                const float* u1c = U1 + s * 2;
                #pragma unroll
                for (int k2 = 0; k2 < 16; ++k2) {
                    vfloat2 a2 = { rl(hval, 2 * k2), rl(hval, 2 * k2 + 1) };
                    vfloat2 u2 = *(const vfloat2*)(u1c + k2 * 64);
                    gAcc = vfma2(a2, u2, gAcc);
                }
            }
            const float zr  = fast_sigmoid(gAcc.x + gAcc.y);   // z (g=0) | r (g=1)
            const float r_s = __shfl(zr, 32 + s, 64);
            const float z_s = __shfl(zr, s, 64);
            const float rh  = r_s * hval;
            {
                const float* uhc = sU + 2048 + s * 2;
                #pragma unroll
                for (int k2 = 0; k2 < 16; ++k2) {
                    vfloat2 a2 = { rl(rh, 2 * k2), rl(rh, 2 * k2 + 1) };
                    vfloat2 u2 = *(const vfloat2*)(uhc + k2 * 64);
                    hAcc = vfma2(a2, u2, hAcc);
                }
            }
            const float hh   = fast_tanh(hAcc.x + hAcc.y);
            const float hnew = fmaf(z_s, hval - hh, hh);       // z*h + (1-z)*hh
            if (g == 0) st_dev(&hn[n * S + s], hnew);
            hval = hnew;                                       // identical in both halves

            const float* t = hp; hp = hn; hn = (float*)t;      // swap

            if (l != 2 || it != 4) {                           // no barrier after last iter
                gbar(p.bar, phase, b); phase++;
            }
        }
    }

    // ---- epilogue in-register: node 5 = block 0, wave 5 (hval holds final h)
    if (b == 0 && wid == 5) {
        float y[5];
        #pragma unroll
        for (int j = 0; j < 5; ++j) y[j] = hval * p.ow[s * 5 + j];
        #pragma unroll
        for (int off = 1; off < 32; off <<= 1) {
            #pragma unroll
            for (int j = 0; j < 5; ++j) y[j] += __shfl_xor(y[j], off, 64);
        }
        #pragma unroll
        for (int j = 0; j < 5; ++j) y[j] += p.ob[j];
        float m = -1e30f;
        #pragma unroll
        for (int j = 0; j < 5; ++j) m = fmaxf(m, y[j]);
        float ssum = 0.f;
        #pragma unroll
        for (int j = 0; j < 5; ++j) ssum += __expf(y[j] - m);
        float lse = m + __logf(ssum);
        #pragma unroll
        for (int j = 0; j < 5; ++j) if (lane == j) p.out[j] = y[j] - lse;
    }
}

// ---------------------------------------------------------------------------
// Fallback chain — host launches it only if hipLaunchCooperativeKernel reports
// a synchronous rejection. Known-good round-3/5 structure.
// ---------------------------------------------------------------------------
__global__ __launch_bounds__(256) void init_h_fb(const float* __restrict__ x,
                                                 const float* __restrict__ fcw,
                                                 const float* __restrict__ fcb,
                                                 float* __restrict__ h0) {
    int t = blockIdx.x * 256 + threadIdx.x;
    int s = t & 31;
    int n = t >> 5;
    float acc = fcb[s];
    #pragma unroll 8
    for (int k = 0; k < FIN; ++k)
        acc = fmaf(x[n * FIN + k], fcw[k * S + s], acc);
    h0[n * S + s] = acc;
}

__global__ __launch_bounds__(512) void ggnn_iter_fb(
    const float* __restrict__ hprev, float* __restrict__ hnext,
    const int* __restrict__ deg, const int* __restrict__ csr,
    const float* __restrict__ wz, const float* __restrict__ wr, const float* __restrict__ wh,
    const float* __restrict__ uz, const float* __restrict__ ur, const float* __restrict__ uh,
    const float* __restrict__ bz, const float* __restrict__ br) {
    __shared__ __align__(16) float sWz[4096];
    __shared__ __align__(16) float sWr[4096];
    __shared__ __align__(16) float sWh[4096];
    __shared__ __align__(16) float sUz[1024], sUr[1024], sUh[1024];

    int tid = threadIdx.x;
    {
        float4*       dz = (float4*)sWz; const float4* gz = (const float4*)wz;
        float4*       dr = (float4*)sWr; const float4* gr = (const float4*)wr;
        float4*       dh = (float4*)sWh; const float4* gh = (const float4*)wh;
        for (int i = tid; i < 1024; i += 512) { dz[i] = gz[i]; dr[i] = gr[i]; dh[i] = gh[i]; }
        float4*       duz = (float4*)sUz; const float4* guz = (const float4*)uz;
        float4*       dur = (float4*)sUr; const float4* gur = (const float4*)ur;
        float4*       duh = (float4*)sUh; const float4* guh = (const float4*)uh;
        if (tid < 256) { duz[tid] = guz[tid]; dur[tid] = gur[tid]; duh[tid] = guh[tid]; }
    }
    __syncthreads();

    const int wid  = tid >> 6;
    const int lane = tid & 63;
    const int s    = lane & 31;
    const int g    = lane >> 5;
    const int n    = blockIdx.x * 8 + wid;

    const int d1 = min(deg[g * N + n], CAP);
    const int d2 = min(deg[(g + 2) * N + n], CAP);
    const int* __restrict__ l1 = csr + (g * N + n) * CAP;
    const int* __restrict__ l2 = csr + ((g + 2) * N + n) * CAP;
    float acc0 = 0.f, acc1 = 0.f;
    const int dmax = max(d1, d2);
    for (int i = 0; i < dmax; ++i) {
        if (i < d1) acc0 += hprev[l1[i] * S + s];
        if (i < d2) acc1 += hprev[l2[i] * S + s];
    }
    const float hval = hprev[n * S + s];

    const float* __restrict__ W1 = g ? sWr : sWz;
    const float* __restrict__ U1 = g ? sUr : sUz;
    float accA = g ? br[s] : bz[s];
    float accB = 0.f;
    float hA = 0.f, hB = 0.f;
    #pragma unroll
    for (int e = 0; e < E; ++e) {
        const float src = (e < 2) ? acc0 : acc1;
        const float* w1c = W1 + e * 1024 + s;
        const float* whc = sWh + e * 1024 + s;
        #pragma unroll
        for (int k = 0; k < 32; k += 2) {
            float a0 = rl(src, (e & 1) * 32 + k);
            float a1 = rl(src, (e & 1) * 32 + k + 1);
            accA = fmaf(a0, w1c[(k)     * 32], accA);
            accB = fmaf(a1, w1c[(k + 1) * 32], accB);
            hA   = fmaf(a0, whc[(k)     * 32], hA);
            hB   = fmaf(a1, whc[(k + 1) * 32], hB);
        }
    }
    #pragma unroll
    for (int k = 0; k < 32; k += 2) {
        accA = fmaf(rl(hval, k),     U1[(k)     * 32 + s], accA);
        accB = fmaf(rl(hval, k + 1), U1[(k + 1) * 32 + s], accB);
    }
    const float zr  = fast_sigmoid(accA + accB);
    const float r_s = __shfl(zr, 32 + s, 64);
    const float z_s = __shfl(zr, s, 64);
    const float rh  = r_s * hval;
    #pragma unroll
    for (int k = 0; k < 32; k += 2) {
        hA = fmaf(rl(rh, k),     sUh[(k)     * 32 + s], hA);
        hB = fmaf(rl(rh, k + 1), sUh[(k + 1) * 32 + s], hB);
    }
    const float hh = fast_tanh(hA + hB);
    const float hnew = fmaf(z_s, hval - hh, hh);
    if (g == 0) hnext[n * S + s] = hnew;
}

__global__ void epilogue_fb(const float* __restrict__ h,
                            const float* __restrict__ ow, const float* __restrict__ ob,
                            float* __restrict__ out) {
    int lane = threadIdx.x;
    float y = 0.f;
    if (lane < 5) {
        y = ob[lane];
        for (int k = 0; k < 32; ++k)
            y = fmaf(h[5 * S + k], ow[k * 5 + lane], y);
    }
    float m = -1e30f;
    #pragma unroll
    for (int j = 0; j < 5; ++j) m = fmaxf(m, __shfl(y, j, 64));
    float ssum = 0.f;
    #pragma unroll
    for (int j = 0; j < 5; ++j) ssum += __expf(__shfl(y, j, 64) - m);
    float lse = m + __logf(ssum);
    if (lane < 5) out[lane] = y - lse;
}

extern "C" void kernel_launch(void* const* d_in, const int* in_sizes, int n_in,
                              void* d_out, int out_size, void* d_ws, size_t ws_size,
                              hipStream_t stream) {
    const float* x     = (const float*)d_in[0];
    // d_in[1] = x_lengths (int32) — unused by the reference
    const float* edges = (const float*)d_in[2];
    const float* fcw   = (const float*)d_in[3];
    const float* fcb   = (const float*)d_in[4];
    const float* wz    = (const float*)d_in[5];
    const float* wr    = (const float*)d_in[6];
    const float* wh    = (const float*)d_in[7];
    const float* uz    = (const float*)d_in[8];
    const float* ur    = (const float*)d_in[9];
    const float* uh    = (const float*)d_in[10];
    const float* bz    = (const float*)d_in[11];
    const float* br    = (const float*)d_in[12];
    const float* ow    = (const float*)d_in[13];
    const float* ob    = (const float*)d_in[14];

    char* ws = (char*)d_ws;
    float* h0  = (float*)(ws);                   // 3073 rows * 32 * 4 = 393,344 B
    float* h1  = (float*)(ws + 393600);
    int*   deg = (int*)(ws + 787200);            // 49,152 B
    int*   bar = (int*)(ws + 836352);            // 4,096 B tree-barrier lines
    int*   csr = (int*)(ws + 840448);            // 3,145,728 B -> end 3,986,176

    hipMemsetAsync(deg, 0, 49152 + 4096, stream);   // deg + bar contiguous
    build_csr<<<36864, 256, 0, stream>>>(edges, deg, csr);

    Params p;
    p.x = x; p.fcw = fcw; p.fcb = fcb;
    p.wz = wz; p.wr = wr; p.wh = wh;
    p.uz = uz; p.ur = ur; p.uh = uh;
    p.bz = bz; p.br = br; p.ow = ow; p.ob = ob;
    p.deg = deg; p.csr = csr; p.bar = bar;
    p.h0 = h0; p.h1 = h1; p.out = (float*)d_out;

    void* args[] = { &p };
    hipError_t err = hipLaunchCooperativeKernel((const void*)fused_ggnn,
                                                dim3(BLK), dim3(TPB), args, 0, stream);
    if (err != hipSuccess) {
        // Launch rejected synchronously -> known-good multi-dispatch path.
        init_h_fb<<<384, 256, 0, stream>>>(x, fcw, fcb, h0);
        float* ha = h0;
        float* hb = h1;
        for (int l = 0; l < 3; ++l) {
            for (int it = 0; it < 5; ++it) {
                ggnn_iter_fb<<<384, 512, 0, stream>>>(ha, hb, deg, csr,
                    wz + l * 4096, wr + l * 4096, wh + l * 4096,
                    uz + l * 1024, ur + l * 1024, uh + l * 1024,
                    bz + l * 32, br + l * 32);
                float* t = ha; ha = hb; hb = t;
            }
        }
        epilogue_fb<<<1, 64, 0, stream>>>(ha, ow, ob, (float*)d_out);
    }
}